// Round 13
// baseline (278.898 us; speedup 1.0000x reference)
//
#include <hip/hip_runtime.h>
#include <type_traits>
#include <utility>

#define B_ 4
#define T_ 160
#define S_ 80
#define F_ 640
#define H_ 1024
#define V_ 1024

typedef float f32x4 __attribute__((ext_vector_type(4)));
typedef short s16x8 __attribute__((ext_vector_type(8)));
typedef __bf16 bf16x8_t __attribute__((ext_vector_type(8)));

// ---- MFMA wrapper: hedge between V8s (short) and V8y (__bf16) builtin signatures ----
template <typename T, typename = void>
struct MfmaTakes : std::false_type {};
template <typename T>
struct MfmaTakes<T, std::void_t<decltype(__builtin_amdgcn_mfma_f32_16x16x32_bf16(
    std::declval<T>(), std::declval<T>(), std::declval<f32x4>(), 0, 0, 0))>>
    : std::true_type {};

template <typename S8>
__device__ __forceinline__ f32x4 mfma_bf16_16x16x32(S8 a, S8 b, f32x4 c) {
  if constexpr (MfmaTakes<S8>::value) {
    return __builtin_amdgcn_mfma_f32_16x16x32_bf16(a, b, c, 0, 0, 0);
  } else {
    return __builtin_amdgcn_mfma_f32_16x16x32_bf16(
        __builtin_bit_cast(bf16x8_t, a), __builtin_bit_cast(bf16x8_t, b), c, 0, 0, 0);
  }
}

// fp32 -> bf16 round-to-nearest-even (no NaN in this workload)
__device__ __forceinline__ unsigned short f2bf(float x) {
  unsigned int u = __float_as_uint(x);
  u += 0x7FFFu + ((u >> 16) & 1u);
  return (unsigned short)(u >> 16);
}

// ---------------------------------------------------------------------------
// Kernel 1: cast W1,W2 to bf16 in fragment-contiguous layout [K/8][N][8]
// so a B-fragment for mfma_16x16x32 is one 16B global load.
// ---------------------------------------------------------------------------
__global__ __launch_bounds__(256) void prep_weights(const float* __restrict__ W1,
                                                    const float* __restrict__ W2,
                                                    s16x8* __restrict__ W1p,
                                                    s16x8* __restrict__ W2p) {
  const int NW1 = (F_ / 8) * H_;   // 81920 chunks
  const int NW2 = (H_ / 8) * V_;   // 131072 chunks
  int c = blockIdx.x * 256 + threadIdx.x;
  if (c < NW1) {
    int kg = c >> 10, v = c & 1023;
    s16x8 o;
#pragma unroll
    for (int i = 0; i < 8; ++i) o[i] = (short)f2bf(W1[(kg * 8 + i) * H_ + v]);
    W1p[c] = o;
  } else if (c < NW1 + NW2) {
    int c2 = c - NW1;
    int kg = c2 >> 10, v = c2 & 1023;
    s16x8 o;
#pragma unroll
    for (int i = 0; i < 8; ++i) o[i] = (short)f2bf(W2[(kg * 8 + i) * V_ + v]);
    W2p[c2] = o;
  }
}

// ---------------------------------------------------------------------------
// Kernel 2: P = src@W1 + b1 (640 rows), Q = tgt@W1 (320 rows), fp32 out.
// 15 WGs x 512 thr; BM=64, 8 waves col-split (128 cols each); 16x16x32 MFMA.
// ---------------------------------------------------------------------------
__global__ __launch_bounds__(512, 2) void pq_gemm(const float* __restrict__ src,
                                                  const float* __restrict__ tgt,
                                                  const s16x8* __restrict__ W1p,
                                                  const float* __restrict__ b1,
                                                  float* __restrict__ P,
                                                  float* __restrict__ Q) {
  __shared__ s16x8 a_lds[64 * 80];  // 80 KB: rows m, 80 k-chunks, swizzled
  const int tid = threadIdx.x;
  const int wr = blockIdx.x;
  const int r0 = wr * 64;
  const bool isP = (wr < 10);  // rows 0..639 are src, 640..959 are tgt

  for (int c = tid; c < 64 * 80; c += 512) {
    int m = c / 80, kg8 = c - m * 80;
    int R = r0 + m;
    const float* rowp = isP ? (src + R * F_) : (tgt + (R - 640) * F_);
    const f32x4* p4 = (const f32x4*)(rowp + kg8 * 8);
    f32x4 x0 = p4[0], x1 = p4[1];
    s16x8 o;
#pragma unroll
    for (int i = 0; i < 4; ++i) o[i] = (short)f2bf(x0[i]);
#pragma unroll
    for (int i = 0; i < 4; ++i) o[4 + i] = (short)f2bf(x1[i]);
    a_lds[m * 80 + (kg8 ^ (m & 7))] = o;
  }
  __syncthreads();

  const int l = tid & 63, wv = tid >> 6;
  const int g = l >> 4, cl = l & 15;
  const f32x4 zero = {0.f, 0.f, 0.f, 0.f};
  f32x4 acc[4][8];
#pragma unroll
  for (int rt = 0; rt < 4; ++rt)
#pragma unroll
    for (int ct = 0; ct < 8; ++ct) acc[rt][ct] = zero;

  const s16x8* bbase = W1p + g * 1024 + wv * 128 + cl;
  s16x8 bA[8], bB[8], af[4];
#pragma unroll
  for (int ct = 0; ct < 8; ++ct) bA[ct] = bbase[ct * 16];

  for (int ks = 0; ks < 20; ks += 2) {
#pragma unroll
    for (int ct = 0; ct < 8; ++ct) bB[ct] = bbase[(ks + 1) * 4096 + ct * 16];
#pragma unroll
    for (int rt = 0; rt < 4; ++rt) {
      int m = rt * 16 + cl;
      af[rt] = a_lds[m * 80 + ((ks * 4 + g) ^ (m & 7))];
    }
#pragma unroll
    for (int ct = 0; ct < 8; ++ct)
#pragma unroll
      for (int rt = 0; rt < 4; ++rt)
        acc[rt][ct] = mfma_bf16_16x16x32(af[rt], bA[ct], acc[rt][ct]);
    int ksn = (ks + 2 < 20) ? (ks + 2) : 0;  // dummy reload on last iter
#pragma unroll
    for (int ct = 0; ct < 8; ++ct) bA[ct] = bbase[ksn * 4096 + ct * 16];
#pragma unroll
    for (int rt = 0; rt < 4; ++rt) {
      int m = rt * 16 + cl;
      af[rt] = a_lds[m * 80 + (((ks + 1) * 4 + g) ^ (m & 7))];
    }
#pragma unroll
    for (int ct = 0; ct < 8; ++ct)
#pragma unroll
      for (int rt = 0; rt < 4; ++rt)
        acc[rt][ct] = mfma_bf16_16x16x32(af[rt], bB[ct], acc[rt][ct]);
  }

  float b1v[8];
#pragma unroll
  for (int ct = 0; ct < 8; ++ct) b1v[ct] = isP ? b1[wv * 128 + ct * 16 + cl] : 0.f;
  float* outbase = isP ? P : Q;
  const int orow0 = isP ? r0 : (r0 - 640);
#pragma unroll
  for (int rt = 0; rt < 4; ++rt) {
#pragma unroll
    for (int j = 0; j < 4; ++j) {
      int row = rt * 16 + g * 4 + j;
      float* op = outbase + (size_t)(orow0 + row) * H_ + wv * 128 + cl;
#pragma unroll
      for (int ct = 0; ct < 8; ++ct) op[ct * 16] = acc[rt][ct][j] + b1v[ct];
    }
  }
}

// ---------------------------------------------------------------------------
// Kernel 3: LOGITS-ONLY GEMM (softmax split out). The fused design has a
// structural ~25% MfmaUtil ceiling: full-V-per-WG (softmax) + reg/LDS caps
// force <=64 rows/WG -> 64KB unique B per 512 MFMA-cyc round = 125 B/cyc/CU
// demand vs ~29 sustainable (R5-R12). Decoupling removes the constraint:
// tile 256r x 128c -> unique B = 410 MB total; the 4 same-col-band waves
// load IDENTICAL B addresses (L1-served).
//   1600 WGs (200 rowtiles x 8 coltiles) x 512 thr; 8 waves = 4wr x 2wc,
//   wave = 64r x 64c, acc[4][4] = 64 AGPR. h built per-kstep into dbuf
//   LDS chunk [2][256r][5 chunks] (40 KB -> 2 WGs/CU; stride 5 = 2-way
//   bank-free, affine addressing). Only 40 P/Q source rows per tile ->
//   build traffic tiny. Logits (f32, +b2) -> d_out; lse_sub finishes.
// Canary: FETCH small / WRITE ~209.7 MB; inflation = spill = revert.
// ---------------------------------------------------------------------------
__global__ __launch_bounds__(512, 2) void logits_gemm(const float* __restrict__ Pm,
                                                      const float* __restrict__ Qm,
                                                      const s16x8* __restrict__ W2p,
                                                      const float* __restrict__ b2,
                                                      float* __restrict__ out) {
  __shared__ s16x8 h_lds[2][256 * 5];  // 40,960 B
  const int tid = threadIdx.x;
  int bx = blockIdx.x;
  int wg = (bx & 7) * 200 + (bx >> 3);  // XCD swizzle (1600 % 8 == 0)
  const int rowtile = wg >> 3, coltile = wg & 7;
  const int b = rowtile / 50;
  int rr = rowtile - b * 50;
  const int t0 = (rr / 10) * 32;
  const int s0 = (rr - (rr / 10) * 10) * 8;

  const int l = tid & 63, wv = tid >> 6;
  const int g = l >> 4, cl = l & 15;
  const int wr = wv >> 1, wc = wv & 1;  // 4 row-bands x 2 col-bands

  f32x4 acc[4][4];
#pragma unroll
  for (int rt = 0; rt < 4; ++rt)
#pragma unroll
    for (int ct = 0; ct < 4; ++ct) acc[rt][ct] = {0.f, 0.f, 0.f, 0.f};

  // B chunk base: (ks*4+g)*1024 + coltile*128 + wc*64 + ct*16 + cl
  const s16x8* bb = W2p + g * 1024 + coltile * 128 + wc * 64 + cl;
  // A base for this wave's row-band (row256 = wr*64 + rt*16 + cl)
  const int arow = (wr * 64 + cl) * 5 + g;

  // h-build for kstep ks into buffer bsel: 1024 chunks, 2 per thread
#define BUILD(ks, bsel)                                                         \
  {                                                                             \
    _Pragma("unroll")                                                           \
    for (int i = 0; i < 2; ++i) {                                               \
      int c = tid + 512 * i;                                                    \
      int row = c >> 2, kg = c & 3;                                             \
      int dt = row >> 3, ds = row & 7;                                          \
      const f32x4* p4 = (const f32x4*)(Pm + (size_t)(b * T_ + t0 + dt) * H_ +   \
                                       (ks) * 32 + kg * 8);                     \
      const f32x4* q4 = (const f32x4*)(Qm + (size_t)(b * S_ + s0 + ds) * H_ +   \
                                       (ks) * 32 + kg * 8);                     \
      f32x4 x0 = p4[0] + q4[0];                                                 \
      f32x4 x1 = p4[1] + q4[1];                                                 \
      s16x8 o;                                                                  \
      _Pragma("unroll")                                                         \
      for (int e = 0; e < 4; ++e) o[e] = (short)f2bf(fmaxf(x0[e], 0.f));        \
      _Pragma("unroll")                                                         \
      for (int e = 0; e < 4; ++e) o[4 + e] = (short)f2bf(fmaxf(x1[e], 0.f));    \
      h_lds[bsel][row * 5 + kg] = o;                                            \
    }                                                                           \
  }

  BUILD(0, 0);
  __syncthreads();

  for (int ks = 0; ks < 32; ++ks) {
    if (ks + 1 < 32) BUILD(ks + 1, (ks + 1) & 1);
    const s16x8* base = bb + ks * 4096;
    s16x8 bf0 = base[0];
    s16x8 bf1 = base[16];
    s16x8 bf2 = base[32];
    s16x8 bf3 = base[48];
    const s16x8* ap = &h_lds[ks & 1][arow];
    s16x8 a0 = ap[0];
    s16x8 a1 = ap[16 * 5];
    s16x8 a2 = ap[32 * 5];
    s16x8 a3 = ap[48 * 5];
    acc[0][0] = mfma_bf16_16x16x32(a0, bf0, acc[0][0]);
    acc[1][0] = mfma_bf16_16x16x32(a1, bf0, acc[1][0]);
    acc[2][0] = mfma_bf16_16x16x32(a2, bf0, acc[2][0]);
    acc[3][0] = mfma_bf16_16x16x32(a3, bf0, acc[3][0]);
    acc[0][1] = mfma_bf16_16x16x32(a0, bf1, acc[0][1]);
    acc[1][1] = mfma_bf16_16x16x32(a1, bf1, acc[1][1]);
    acc[2][1] = mfma_bf16_16x16x32(a2, bf1, acc[2][1]);
    acc[3][1] = mfma_bf16_16x16x32(a3, bf1, acc[3][1]);
    acc[0][2] = mfma_bf16_16x16x32(a0, bf2, acc[0][2]);
    acc[1][2] = mfma_bf16_16x16x32(a1, bf2, acc[1][2]);
    acc[2][2] = mfma_bf16_16x16x32(a2, bf2, acc[2][2]);
    acc[3][2] = mfma_bf16_16x16x32(a3, bf2, acc[3][2]);
    acc[0][3] = mfma_bf16_16x16x32(a0, bf3, acc[0][3]);
    acc[1][3] = mfma_bf16_16x16x32(a1, bf3, acc[1][3]);
    acc[2][3] = mfma_bf16_16x16x32(a2, bf3, acc[2][3]);
    acc[3][3] = mfma_bf16_16x16x32(a3, bf3, acc[3][3]);
    __syncthreads();
  }
#undef BUILD

  // epilogue: + b2, store f32 logits
  float bv[4];
#pragma unroll
  for (int ct = 0; ct < 4; ++ct) bv[ct] = b2[coltile * 128 + wc * 64 + ct * 16 + cl];
#pragma unroll
  for (int rt = 0; rt < 4; ++rt)
#pragma unroll
    for (int j = 0; j < 4; ++j) {
      int row256 = wr * 64 + rt * 16 + g * 4 + j;
      int dt = row256 >> 3, ds = row256 & 7;
      int n = (b * T_ + t0 + dt) * S_ + s0 + ds;
      float* op = out + (size_t)n * V_ + coltile * 128 + wc * 64 + cl;
#pragma unroll
      for (int ct = 0; ct < 4; ++ct) op[ct * 16] = acc[rt][ct][j] + bv[ct];
    }
}

// ---------------------------------------------------------------------------
// Kernel 4: row-wise log_softmax finish, IN PLACE on d_out.
// One row per wave (4 rows/block). Each lane reads/writes only its own 16
// elements -> race-free in-place. 420 MB streaming @ HBM.
// ---------------------------------------------------------------------------
__global__ __launch_bounds__(256) void lse_sub(float* __restrict__ out) {
  const int wv = threadIdx.x >> 6, l = threadIdx.x & 63;
  const size_t n = (size_t)blockIdx.x * 4 + wv;
  float* row = out + n * V_;
  f32x4 v[4];
#pragma unroll
  for (int i = 0; i < 4; ++i) v[i] = ((const f32x4*)row)[l + 64 * i];

  float m = v[0][0];
#pragma unroll
  for (int i = 0; i < 4; ++i)
#pragma unroll
    for (int j = 0; j < 4; ++j) m = fmaxf(m, v[i][j]);
#pragma unroll
  for (int msk = 1; msk < 64; msk <<= 1) m = fmaxf(m, __shfl_xor(m, msk, 64));

  float s = 0.f;
#pragma unroll
  for (int i = 0; i < 4; ++i)
#pragma unroll
    for (int j = 0; j < 4; ++j) s += __expf(v[i][j] - m);
#pragma unroll
  for (int msk = 1; msk < 64; msk <<= 1) s += __shfl_xor(s, msk, 64);

  const float lse = m + __logf(s);
#pragma unroll
  for (int i = 0; i < 4; ++i) {
    f32x4 o = v[i];
#pragma unroll
    for (int j = 0; j < 4; ++j) o[j] -= lse;
    ((f32x4*)row)[l + 64 * i] = o;
  }
}

// ---------------------------------------------------------------------------
extern "C" void kernel_launch(void* const* d_in, const int* in_sizes, int n_in,
                              void* d_out, int out_size, void* d_ws, size_t ws_size,
                              hipStream_t stream) {
  const float* src = (const float*)d_in[0];  // [4,160,640]
  const float* tgt = (const float*)d_in[1];  // [4,80,640]
  const float* W1  = (const float*)d_in[2];  // [640,1024]
  const float* b1  = (const float*)d_in[3];  // [1024]
  const float* W2  = (const float*)d_in[4];  // [1024,1024]
  const float* b2  = (const float*)d_in[5];  // [1024]
  float* out = (float*)d_out;

  char* ws = (char*)d_ws;
  s16x8* W1p = (s16x8*)(ws);             // 1,310,720 B
  s16x8* W2p = (s16x8*)(ws + 1310720);   // 2,097,152 B
  float* P   = (float*)(ws + 3407872);   // 2,621,440 B  (src@W1 + b1)
  float* Q   = (float*)(ws + 6029312);   // 1,310,720 B  (tgt@W1)
  // total ws use: 7,340,032 B

  prep_weights<<<832, 256, 0, stream>>>(W1, W2, W1p, W2p);
  pq_gemm<<<15, 512, 0, stream>>>(src, tgt, W1p, b1, P, Q);
  logits_gemm<<<1600, 512, 0, stream>>>(P, Q, W2p, b2, out);
  lse_sub<<<12800, 256, 0, stream>>>(out);
}

// Round 14
// 271.378 us; speedup vs baseline: 1.0277x; 1.0277x over previous
//
#include <hip/hip_runtime.h>
#include <type_traits>
#include <utility>

#define B_ 4
#define T_ 160
#define S_ 80
#define F_ 640
#define H_ 1024
#define V_ 1024

typedef float f32x4 __attribute__((ext_vector_type(4)));
typedef short s16x8 __attribute__((ext_vector_type(8)));
typedef __bf16 bf16x8_t __attribute__((ext_vector_type(8)));

// ---- MFMA wrapper: hedge between V8s (short) and V8y (__bf16) builtin signatures ----
template <typename T, typename = void>
struct MfmaTakes : std::false_type {};
template <typename T>
struct MfmaTakes<T, std::void_t<decltype(__builtin_amdgcn_mfma_f32_16x16x32_bf16(
    std::declval<T>(), std::declval<T>(), std::declval<f32x4>(), 0, 0, 0))>>
    : std::true_type {};

template <typename S8>
__device__ __forceinline__ f32x4 mfma_bf16_16x16x32(S8 a, S8 b, f32x4 c) {
  if constexpr (MfmaTakes<S8>::value) {
    return __builtin_amdgcn_mfma_f32_16x16x32_bf16(a, b, c, 0, 0, 0);
  } else {
    return __builtin_amdgcn_mfma_f32_16x16x32_bf16(
        __builtin_bit_cast(bf16x8_t, a), __builtin_bit_cast(bf16x8_t, b), c, 0, 0, 0);
  }
}

// fp32 -> bf16 round-to-nearest-even (no NaN in this workload)
__device__ __forceinline__ unsigned short f2bf(float x) {
  unsigned int u = __float_as_uint(x);
  u += 0x7FFFu + ((u >> 16) & 1u);
  return (unsigned short)(u >> 16);
}

// ---------------------------------------------------------------------------
// Kernel 1: cast W1,W2 to bf16 in fragment-contiguous layout [K/8][N][8]
// so a B-fragment for mfma_16x16x32 is one 16B global load.
// ---------------------------------------------------------------------------
__global__ __launch_bounds__(256) void prep_weights(const float* __restrict__ W1,
                                                    const float* __restrict__ W2,
                                                    s16x8* __restrict__ W1p,
                                                    s16x8* __restrict__ W2p) {
  const int NW1 = (F_ / 8) * H_;   // 81920 chunks
  const int NW2 = (H_ / 8) * V_;   // 131072 chunks
  int c = blockIdx.x * 256 + threadIdx.x;
  if (c < NW1) {
    int kg = c >> 10, v = c & 1023;
    s16x8 o;
#pragma unroll
    for (int i = 0; i < 8; ++i) o[i] = (short)f2bf(W1[(kg * 8 + i) * H_ + v]);
    W1p[c] = o;
  } else if (c < NW1 + NW2) {
    int c2 = c - NW1;
    int kg = c2 >> 10, v = c2 & 1023;
    s16x8 o;
#pragma unroll
    for (int i = 0; i < 8; ++i) o[i] = (short)f2bf(W2[(kg * 8 + i) * V_ + v]);
    W2p[c2] = o;
  }
}

// ---------------------------------------------------------------------------
// Kernel 2: P = src@W1 + b1 (640 rows), Q = tgt@W1 (320 rows), fp32 out.
// 15 WGs x 512 thr; BM=64, 8 waves col-split (128 cols each); 16x16x32 MFMA.
// ---------------------------------------------------------------------------
__global__ __launch_bounds__(512, 2) void pq_gemm(const float* __restrict__ src,
                                                  const float* __restrict__ tgt,
                                                  const s16x8* __restrict__ W1p,
                                                  const float* __restrict__ b1,
                                                  float* __restrict__ P,
                                                  float* __restrict__ Q) {
  __shared__ s16x8 a_lds[64 * 80];  // 80 KB: rows m, 80 k-chunks, swizzled
  const int tid = threadIdx.x;
  const int wr = blockIdx.x;
  const int r0 = wr * 64;
  const bool isP = (wr < 10);  // rows 0..639 are src, 640..959 are tgt

  for (int c = tid; c < 64 * 80; c += 512) {
    int m = c / 80, kg8 = c - m * 80;
    int R = r0 + m;
    const float* rowp = isP ? (src + R * F_) : (tgt + (R - 640) * F_);
    const f32x4* p4 = (const f32x4*)(rowp + kg8 * 8);
    f32x4 x0 = p4[0], x1 = p4[1];
    s16x8 o;
#pragma unroll
    for (int i = 0; i < 4; ++i) o[i] = (short)f2bf(x0[i]);
#pragma unroll
    for (int i = 0; i < 4; ++i) o[4 + i] = (short)f2bf(x1[i]);
    a_lds[m * 80 + (kg8 ^ (m & 7))] = o;
  }
  __syncthreads();

  const int l = tid & 63, wv = tid >> 6;
  const int g = l >> 4, cl = l & 15;
  const f32x4 zero = {0.f, 0.f, 0.f, 0.f};
  f32x4 acc[4][8];
#pragma unroll
  for (int rt = 0; rt < 4; ++rt)
#pragma unroll
    for (int ct = 0; ct < 8; ++ct) acc[rt][ct] = zero;

  const s16x8* bbase = W1p + g * 1024 + wv * 128 + cl;
  s16x8 bA[8], bB[8], af[4];
#pragma unroll
  for (int ct = 0; ct < 8; ++ct) bA[ct] = bbase[ct * 16];

  for (int ks = 0; ks < 20; ks += 2) {
#pragma unroll
    for (int ct = 0; ct < 8; ++ct) bB[ct] = bbase[(ks + 1) * 4096 + ct * 16];
#pragma unroll
    for (int rt = 0; rt < 4; ++rt) {
      int m = rt * 16 + cl;
      af[rt] = a_lds[m * 80 + ((ks * 4 + g) ^ (m & 7))];
    }
#pragma unroll
    for (int ct = 0; ct < 8; ++ct)
#pragma unroll
      for (int rt = 0; rt < 4; ++rt)
        acc[rt][ct] = mfma_bf16_16x16x32(af[rt], bA[ct], acc[rt][ct]);
    int ksn = (ks + 2 < 20) ? (ks + 2) : 0;  // dummy reload on last iter
#pragma unroll
    for (int ct = 0; ct < 8; ++ct) bA[ct] = bbase[ksn * 4096 + ct * 16];
#pragma unroll
    for (int rt = 0; rt < 4; ++rt) {
      int m = rt * 16 + cl;
      af[rt] = a_lds[m * 80 + (((ks + 1) * 4 + g) ^ (m & 7))];
    }
#pragma unroll
    for (int ct = 0; ct < 8; ++ct)
#pragma unroll
      for (int rt = 0; rt < 4; ++rt)
        acc[rt][ct] = mfma_bf16_16x16x32(af[rt], bB[ct], acc[rt][ct]);
  }

  float b1v[8];
#pragma unroll
  for (int ct = 0; ct < 8; ++ct) b1v[ct] = isP ? b1[wv * 128 + ct * 16 + cl] : 0.f;
  float* outbase = isP ? P : Q;
  const int orow0 = isP ? r0 : (r0 - 640);
#pragma unroll
  for (int rt = 0; rt < 4; ++rt) {
#pragma unroll
    for (int j = 0; j < 4; ++j) {
      int row = rt * 16 + g * 4 + j;
      float* op = outbase + (size_t)(orow0 + row) * H_ + wv * 128 + cl;
#pragma unroll
      for (int ct = 0; ct < 8; ++ct) op[ct * 16] = acc[rt][ct][j] + b1v[ct];
    }
  }
}

// ---------------------------------------------------------------------------
// Kernel 3: LOGITS-ONLY GEMM, rt=8. The universal ~25% MfmaUtil across
// R5-R13 is the L1 RETURN-PATH wall: every config filled B-frags from
// global at 64 KB per CU k-step round (~1024 cyc @64B/cyc, hits included)
// vs ~310 cyc of MFMA. The only lever is B-reuse per fill = rt (row-frags
// per wave). rt=8 halves B-fill (32 KB -> ~512 cyc), balancing A-LDS reads
// (64 KB @128B/cyc = 512 cyc) -> ceiling ~60%.
//   800 WGs (200 rowtiles x 4 coltiles) x 512 thr; 8 waves = 2wr x 4wc;
//   wave = 128r x 64c; acc[8][4] = 128 AGPR + ~90 VGPR = ~218 regs ->
//   1 WG/CU (2 waves/SIMD, 256-reg cap) enforced by register pressure.
//   B next-kstep prefetched in regs; h built per-kstep into dbuf LDS
//   [2][256r][5ch] (40 KB); h-build replication now 4x (was 8x in R13).
// Canary: FETCH small / WRITE ~205 MB exact; inflation = spill = revert.
// ---------------------------------------------------------------------------
__global__ __launch_bounds__(512, 2) void logits_gemm(const float* __restrict__ Pm,
                                                      const float* __restrict__ Qm,
                                                      const s16x8* __restrict__ W2p,
                                                      const float* __restrict__ b2,
                                                      float* __restrict__ out) {
  __shared__ s16x8 h_lds[2][256 * 5];  // 40,960 B
  const int tid = threadIdx.x;
  int bx = blockIdx.x;
  int wg = (bx & 7) * 100 + (bx >> 3);  // XCD swizzle (800 % 8 == 0)
  const int rowtile = wg >> 2, coltile = wg & 3;
  const int b = rowtile / 50;
  int rr = rowtile - b * 50;
  const int t0 = (rr / 10) * 32;
  const int s0 = (rr - (rr / 10) * 10) * 8;

  const int l = tid & 63, wv = tid >> 6;
  const int g = l >> 4, cl = l & 15;
  const int wr = wv >> 2, wc = wv & 3;  // 2 row-bands x 4 col-bands

  f32x4 acc[8][4];
#pragma unroll
  for (int rt = 0; rt < 8; ++rt)
#pragma unroll
    for (int ct = 0; ct < 4; ++ct) acc[rt][ct] = {0.f, 0.f, 0.f, 0.f};

  // B chunk base: (ks*4+g)*1024 + coltile*256 + wc*64 + ct*16 + cl
  const s16x8* bb = W2p + g * 1024 + coltile * 256 + wc * 64 + cl;
  // A base for this wave's row-band (row256 = wr*128 + rt*16 + cl)
  const int arow = (wr * 128 + cl) * 5 + g;

  // h-build for kstep ks into buffer bsel: 1024 chunks, 2 per thread.
  // P/Q loads have few unique addresses per wave -> TA dedup, L1-cheap.
#define BUILD(ks, bsel)                                                         \
  {                                                                             \
    _Pragma("unroll")                                                           \
    for (int i = 0; i < 2; ++i) {                                               \
      int c = tid + 512 * i;                                                    \
      int row = c >> 2, kg = c & 3;                                             \
      int dt = row >> 3, ds = row & 7;                                          \
      const f32x4* p4 = (const f32x4*)(Pm + (size_t)(b * T_ + t0 + dt) * H_ +   \
                                       (ks) * 32 + kg * 8);                     \
      const f32x4* q4 = (const f32x4*)(Qm + (size_t)(b * S_ + s0 + ds) * H_ +   \
                                       (ks) * 32 + kg * 8);                     \
      f32x4 x0 = p4[0] + q4[0];                                                 \
      f32x4 x1 = p4[1] + q4[1];                                                 \
      s16x8 o;                                                                  \
      _Pragma("unroll")                                                         \
      for (int e = 0; e < 4; ++e) o[e] = (short)f2bf(fmaxf(x0[e], 0.f));        \
      _Pragma("unroll")                                                         \
      for (int e = 0; e < 4; ++e) o[4 + e] = (short)f2bf(fmaxf(x1[e], 0.f));    \
      h_lds[bsel][row * 5 + kg] = o;                                            \
    }                                                                           \
  }

  BUILD(0, 0);
  s16x8 bc[4], bn[4];
#pragma unroll
  for (int ct = 0; ct < 4; ++ct) bc[ct] = bb[ct * 16];
  __syncthreads();

#pragma unroll 2
  for (int ks = 0; ks < 32; ++ks) {
    // prefetch next B into regs; build next h tile
    const int ksn = (ks + 1 < 32) ? ks + 1 : 0;  // dummy on last iter
    const s16x8* nb = bb + ksn * 4096;
#pragma unroll
    for (int ct = 0; ct < 4; ++ct) bn[ct] = nb[ct * 16];
    if (ks + 1 < 32) BUILD(ks + 1, (ks + 1) & 1);

    const s16x8* ap = &h_lds[ks & 1][arow];
    s16x8 a0 = ap[0];
    s16x8 a1 = ap[80];
    s16x8 a2 = ap[160];
    s16x8 a3 = ap[240];
    s16x8 a4 = ap[320];
    s16x8 a5 = ap[400];
    s16x8 a6 = ap[480];
    s16x8 a7 = ap[560];
#pragma unroll
    for (int ct = 0; ct < 4; ++ct) {
      acc[0][ct] = mfma_bf16_16x16x32(a0, bc[ct], acc[0][ct]);
      acc[1][ct] = mfma_bf16_16x16x32(a1, bc[ct], acc[1][ct]);
      acc[2][ct] = mfma_bf16_16x16x32(a2, bc[ct], acc[2][ct]);
      acc[3][ct] = mfma_bf16_16x16x32(a3, bc[ct], acc[3][ct]);
      acc[4][ct] = mfma_bf16_16x16x32(a4, bc[ct], acc[4][ct]);
      acc[5][ct] = mfma_bf16_16x16x32(a5, bc[ct], acc[5][ct]);
      acc[6][ct] = mfma_bf16_16x16x32(a6, bc[ct], acc[6][ct]);
      acc[7][ct] = mfma_bf16_16x16x32(a7, bc[ct], acc[7][ct]);
    }
#pragma unroll
    for (int ct = 0; ct < 4; ++ct) bc[ct] = bn[ct];
    __syncthreads();
  }
#undef BUILD

  // epilogue: + b2, store f32 logits
  float bv[4];
#pragma unroll
  for (int ct = 0; ct < 4; ++ct) bv[ct] = b2[coltile * 256 + wc * 64 + ct * 16 + cl];
#pragma unroll
  for (int rt = 0; rt < 8; ++rt)
#pragma unroll
    for (int j = 0; j < 4; ++j) {
      int row256 = wr * 128 + rt * 16 + g * 4 + j;
      int dt = row256 >> 3, ds = row256 & 7;
      int n = (b * T_ + t0 + dt) * S_ + s0 + ds;
      float* op = out + (size_t)n * V_ + coltile * 256 + wc * 64 + cl;
#pragma unroll
      for (int ct = 0; ct < 4; ++ct) op[ct * 16] = acc[rt][ct][j] + bv[ct];
    }
}

// ---------------------------------------------------------------------------
// Kernel 4: row-wise log_softmax finish, IN PLACE on d_out.
// One row per wave (4 rows/block). Each lane reads/writes only its own 16
// elements -> race-free in-place. 420 MB streaming @ HBM.
// ---------------------------------------------------------------------------
__global__ __launch_bounds__(256) void lse_sub(float* __restrict__ out) {
  const int wv = threadIdx.x >> 6, l = threadIdx.x & 63;
  const size_t n = (size_t)blockIdx.x * 4 + wv;
  float* row = out + n * V_;
  f32x4 v[4];
#pragma unroll
  for (int i = 0; i < 4; ++i) v[i] = ((const f32x4*)row)[l + 64 * i];

  float m = v[0][0];
#pragma unroll
  for (int i = 0; i < 4; ++i)
#pragma unroll
    for (int j = 0; j < 4; ++j) m = fmaxf(m, v[i][j]);
#pragma unroll
  for (int msk = 1; msk < 64; msk <<= 1) m = fmaxf(m, __shfl_xor(m, msk, 64));

  float s = 0.f;
#pragma unroll
  for (int i = 0; i < 4; ++i)
#pragma unroll
    for (int j = 0; j < 4; ++j) s += __expf(v[i][j] - m);
#pragma unroll
  for (int msk = 1; msk < 64; msk <<= 1) s += __shfl_xor(s, msk, 64);

  const float lse = m + __logf(s);
#pragma unroll
  for (int i = 0; i < 4; ++i) {
    f32x4 o = v[i];
#pragma unroll
    for (int j = 0; j < 4; ++j) o[j] -= lse;
    ((f32x4*)row)[l + 64 * i] = o;
  }
}

// ---------------------------------------------------------------------------
extern "C" void kernel_launch(void* const* d_in, const int* in_sizes, int n_in,
                              void* d_out, int out_size, void* d_ws, size_t ws_size,
                              hipStream_t stream) {
  const float* src = (const float*)d_in[0];  // [4,160,640]
  const float* tgt = (const float*)d_in[1];  // [4,80,640]
  const float* W1  = (const float*)d_in[2];  // [640,1024]
  const float* b1  = (const float*)d_in[3];  // [1024]
  const float* W2  = (const float*)d_in[4];  // [1024,1024]
  const float* b2  = (const float*)d_in[5];  // [1024]
  float* out = (float*)d_out;

  char* ws = (char*)d_ws;
  s16x8* W1p = (s16x8*)(ws);             // 1,310,720 B
  s16x8* W2p = (s16x8*)(ws + 1310720);   // 2,097,152 B
  float* P   = (float*)(ws + 3407872);   // 2,621,440 B  (src@W1 + b1)
  float* Q   = (float*)(ws + 6029312);   // 1,310,720 B  (tgt@W1)
  // total ws use: 7,340,032 B

  prep_weights<<<832, 256, 0, stream>>>(W1, W2, W1p, W2p);
  pq_gemm<<<15, 512, 0, stream>>>(src, tgt, W1p, b1, P, Q);
  logits_gemm<<<800, 512, 0, stream>>>(P, Q, W2p, b2, out);
  lse_sub<<<12800, 256, 0, stream>>>(out);
}

// Round 15
// 177.350 us; speedup vs baseline: 1.5726x; 1.5302x over previous
//
#include <hip/hip_runtime.h>
#include <type_traits>
#include <utility>

#define B_ 4
#define T_ 160
#define S_ 80
#define F_ 640
#define H_ 1024
#define V_ 1024

typedef float f32x4 __attribute__((ext_vector_type(4)));
typedef short s16x8 __attribute__((ext_vector_type(8)));
typedef __bf16 bf16x8_t __attribute__((ext_vector_type(8)));

// ---- MFMA wrapper: hedge between V8s (short) and V8y (__bf16) builtin signatures ----
template <typename T, typename = void>
struct MfmaTakes : std::false_type {};
template <typename T>
struct MfmaTakes<T, std::void_t<decltype(__builtin_amdgcn_mfma_f32_16x16x32_bf16(
    std::declval<T>(), std::declval<T>(), std::declval<f32x4>(), 0, 0, 0))>>
    : std::true_type {};

template <typename S8>
__device__ __forceinline__ f32x4 mfma_bf16_16x16x32(S8 a, S8 b, f32x4 c) {
  if constexpr (MfmaTakes<S8>::value) {
    return __builtin_amdgcn_mfma_f32_16x16x32_bf16(a, b, c, 0, 0, 0);
  } else {
    return __builtin_amdgcn_mfma_f32_16x16x32_bf16(
        __builtin_bit_cast(bf16x8_t, a), __builtin_bit_cast(bf16x8_t, b), c, 0, 0, 0);
  }
}

// fp32 -> bf16 round-to-nearest-even (no NaN in this workload)
__device__ __forceinline__ unsigned short f2bf(float x) {
  unsigned int u = __float_as_uint(x);
  u += 0x7FFFu + ((u >> 16) & 1u);
  return (unsigned short)(u >> 16);
}

// ---------------------------------------------------------------------------
// Kernel 1: cast W1,W2 to bf16 in fragment-contiguous layout [K/8][N][8]
// so a B-fragment for mfma_16x16x32 is one 16B global load.
// ---------------------------------------------------------------------------
__global__ __launch_bounds__(256) void prep_weights(const float* __restrict__ W1,
                                                    const float* __restrict__ W2,
                                                    s16x8* __restrict__ W1p,
                                                    s16x8* __restrict__ W2p) {
  const int NW1 = (F_ / 8) * H_;   // 81920 chunks
  const int NW2 = (H_ / 8) * V_;   // 131072 chunks
  int c = blockIdx.x * 256 + threadIdx.x;
  if (c < NW1) {
    int kg = c >> 10, v = c & 1023;
    s16x8 o;
#pragma unroll
    for (int i = 0; i < 8; ++i) o[i] = (short)f2bf(W1[(kg * 8 + i) * H_ + v]);
    W1p[c] = o;
  } else if (c < NW1 + NW2) {
    int c2 = c - NW1;
    int kg = c2 >> 10, v = c2 & 1023;
    s16x8 o;
#pragma unroll
    for (int i = 0; i < 8; ++i) o[i] = (short)f2bf(W2[(kg * 8 + i) * V_ + v]);
    W2p[c2] = o;
  }
}

// ---------------------------------------------------------------------------
// Kernel 2 (R15): P = src@W1 + b1 (640 rows), Q = tgt@W1 (320 rows).
// Re-gridded for parallelism: 120 WGs (30 rowtiles x 32 rows, 4 coltiles x
// 256 cols) x 512 thr — was 15 WGs (15/256 CUs busy, ~13 us of idle GPU).
// 8 waves each own 32 cols: acc[2][2] = 16 AGPR; affine padded LDS [32][81]
// (proven pattern from joint_main). W1p re-read 4x across coltiles = 38 MB
// L2, trivial. Est ~4 us.
// ---------------------------------------------------------------------------
__global__ __launch_bounds__(512, 2) void pq_gemm(const float* __restrict__ src,
                                                  const float* __restrict__ tgt,
                                                  const s16x8* __restrict__ W1p,
                                                  const float* __restrict__ b1,
                                                  float* __restrict__ P,
                                                  float* __restrict__ Q) {
  __shared__ s16x8 a_lds[32 * 81];  // 41,472 B, padded rows
  const int tid = threadIdx.x;
  const int wg = blockIdx.x;           // 120 = 30 rowtiles x 4 coltiles
  const int rowtile = wg >> 2, coltile = wg & 3;
  const int r0 = rowtile * 32;
  const bool isP = (r0 < 640);         // tiles don't straddle the 640 boundary
  const float* rowbase = isP ? (src + (size_t)r0 * F_) : (tgt + (size_t)(r0 - 640) * F_);

  // stage A tile (32 rows x 640 k) as bf16 chunks into padded rows
  for (int c = tid; c < 32 * 80; c += 512) {
    int m = c / 80, kg8 = c - m * 80;
    const f32x4* p4 = (const f32x4*)(rowbase + (size_t)m * F_ + kg8 * 8);
    f32x4 x0 = p4[0], x1 = p4[1];
    s16x8 o;
#pragma unroll
    for (int i = 0; i < 4; ++i) o[i] = (short)f2bf(x0[i]);
#pragma unroll
    for (int i = 0; i < 4; ++i) o[4 + i] = (short)f2bf(x1[i]);
    a_lds[m * 81 + kg8] = o;
  }
  __syncthreads();

  const int l = tid & 63, wv = tid >> 6;   // wv owns cols [coltile*256 + wv*32, +32)
  const int g = l >> 4, cl = l & 15;
  f32x4 acc[2][2];
#pragma unroll
  for (int rt = 0; rt < 2; ++rt)
#pragma unroll
    for (int ct = 0; ct < 2; ++ct) acc[rt][ct] = {0.f, 0.f, 0.f, 0.f};

  // B: W1p chunk index = (ks*4+g)*1024 + coltile*256 + wv*32 + ct*16 + cl
  const s16x8* bb = W1p + g * 1024 + coltile * 256 + wv * 32 + cl;
  const s16x8* a0p = a_lds + cl * 81 + g;
  const s16x8* a1p = a_lds + (16 + cl) * 81 + g;

#pragma unroll
  for (int ks = 0; ks < 20; ++ks) {
    s16x8 b0 = bb[ks * 4096];
    s16x8 b1f = bb[ks * 4096 + 16];
    s16x8 a0 = a0p[ks * 4];
    s16x8 a1 = a1p[ks * 4];
    acc[0][0] = mfma_bf16_16x16x32(a0, b0, acc[0][0]);
    acc[1][0] = mfma_bf16_16x16x32(a1, b0, acc[1][0]);
    acc[0][1] = mfma_bf16_16x16x32(a0, b1f, acc[0][1]);
    acc[1][1] = mfma_bf16_16x16x32(a1, b1f, acc[1][1]);
  }

  float bv[2];
#pragma unroll
  for (int ct = 0; ct < 2; ++ct)
    bv[ct] = isP ? b1[coltile * 256 + wv * 32 + ct * 16 + cl] : 0.f;
  float* outbase = isP ? (P + (size_t)r0 * H_) : (Q + (size_t)(r0 - 640) * H_);
#pragma unroll
  for (int rt = 0; rt < 2; ++rt)
#pragma unroll
    for (int j = 0; j < 4; ++j) {
      int row = rt * 16 + g * 4 + j;
      float* op = outbase + (size_t)row * H_ + coltile * 256 + wv * 32 + cl;
      op[0] = acc[rt][0][j] + bv[0];
      op[16] = acc[rt][1][j] + bv[1];
    }
}

// ---------------------------------------------------------------------------
// Kernel 3: fused h-build + GEMM2 + bias + log_softmax.  BYTE-IDENTICAL to
// R9's champion (176.9 us measured, best of 10 structural variants R5-R14).
// Structure: 1600 WGs x 512 thr (8 waves); 32 rows x 1024 cols per WG;
// h_lds 66 KB padded [32][129] -> 2 WGs/CU; affine A-addressing; fully
// unrolled K-loop with phased 4+4 B-frags; setprio around MFMA clusters.
// ---------------------------------------------------------------------------
__global__ __launch_bounds__(512, 2) void joint_main(const float* __restrict__ Pm,
                                                     const float* __restrict__ Qm,
                                                     const s16x8* __restrict__ W2p,
                                                     const float* __restrict__ b2,
                                                     float* __restrict__ out) {
  __shared__ s16x8 h_lds[32 * 129];  // 66048 B, padded rows (129 chunks/row)
  const int tid = threadIdx.x;
  int bx = blockIdx.x;
  int bid = (bx & 7) * 200 + (bx >> 3);  // XCD-contiguous swizzle (1600 % 8 == 0)
  const int b = bid / 400;
  int rem = bid - b * 400;
  const int t0 = (rem / 10) * 4;
  const int s0 = (rem - (rem / 10) * 10) * 8;

  // build h = relu(P[t] + Q[s]) as bf16 into padded rows
  for (int c = tid; c < 32 * 128; c += 512) {
    int m = c >> 7, kg8 = c & 127;
    int dt = m >> 3, ds = m & 7;
    const f32x4* p4 = (const f32x4*)(Pm + (size_t)(b * T_ + t0 + dt) * H_ + kg8 * 8);
    const f32x4* q4 = (const f32x4*)(Qm + (size_t)(b * S_ + s0 + ds) * H_ + kg8 * 8);
    f32x4 x0 = p4[0] + q4[0];
    f32x4 x1 = p4[1] + q4[1];
    s16x8 o;
#pragma unroll
    for (int i = 0; i < 4; ++i) o[i] = (short)f2bf(fmaxf(x0[i], 0.f));
#pragma unroll
    for (int i = 0; i < 4; ++i) o[4 + i] = (short)f2bf(fmaxf(x1[i], 0.f));
    h_lds[m * 129 + kg8] = o;
  }
  __syncthreads();

  const int l = tid & 63, wv = tid >> 6;   // wv in 0..7, owns cols [wv*128, +128)
  const int g = l >> 4, cl = l & 15;
  f32x4 acc[2][8];
#pragma unroll
  for (int rt = 0; rt < 2; ++rt)
#pragma unroll
    for (int ct = 0; ct < 8; ++ct) acc[rt][ct] = {0.f, 0.f, 0.f, 0.f};

  // B: W2p index = (ks*4+g)*1024 + wv*128 + ct*16 + cl  (ks compile-time)
  const s16x8* bb = W2p + g * 1024 + wv * 128 + cl;
  // A: padded-row bases (pure immediate offsets per k-step: +ks*4 chunks)
  const s16x8* a0p = h_lds + cl * 129 + g;
  const s16x8* a1p = h_lds + (16 + cl) * 129 + g;

  s16x8 b0[4], b1[4], af0, af1;
#pragma unroll
  for (int i = 0; i < 4; ++i) b0[i] = bb[i * 16];
  af0 = a0p[0];
  af1 = a1p[0];

#pragma unroll
  for (int ks = 0; ks < 32; ++ks) {
    // phase 0: load this ks' cols 64..127 frags; MFMA cols 0..63
#pragma unroll
    for (int i = 0; i < 4; ++i) b1[i] = bb[ks * 4096 + 64 + i * 16];
    __builtin_amdgcn_s_setprio(1);
#pragma unroll
    for (int i = 0; i < 4; ++i) {
      acc[0][i] = mfma_bf16_16x16x32(af0, b0[i], acc[0][i]);
      acc[1][i] = mfma_bf16_16x16x32(af1, b0[i], acc[1][i]);
    }
    __builtin_amdgcn_s_setprio(0);
    // phase 1: load next ks cols 0..63 + next A-frags; MFMA cols 64..127
    const int ksn = (ks + 1 < 32) ? ks + 1 : 0;  // compile-time select
#pragma unroll
    for (int i = 0; i < 4; ++i) b0[i] = bb[ksn * 4096 + i * 16];
    s16x8 afn0 = a0p[ksn * 4];
    s16x8 afn1 = a1p[ksn * 4];
    __builtin_amdgcn_s_setprio(1);
#pragma unroll
    for (int i = 0; i < 4; ++i) {
      acc[0][4 + i] = mfma_bf16_16x16x32(af0, b1[i], acc[0][4 + i]);
      acc[1][4 + i] = mfma_bf16_16x16x32(af1, b1[i], acc[1][4 + i]);
    }
    __builtin_amdgcn_s_setprio(0);
    af0 = afn0;
    af1 = afn1;
  }

  // ---- epilogue: +b2, row-wise log_softmax across 8 waves, store ----
  __syncthreads();  // all waves done reading h before overlaying reductions
  float* redm = reinterpret_cast<float*>(h_lds);  // [8 waves][32 rows]
  float* reds = redm + 256;                       // [8 waves][32 rows]
  float* gmbuf = reds + 256;                      // [32 rows]
  float* lsebuf = gmbuf + 32;                     // [32 rows]

  // bias
#pragma unroll
  for (int ct = 0; ct < 8; ++ct) {
    float bv = b2[wv * 128 + ct * 16 + cl];
#pragma unroll
    for (int rt = 0; rt < 2; ++rt)
#pragma unroll
      for (int j = 0; j < 4; ++j) acc[rt][ct][j] += bv;
  }

  // per-wave per-row max -> redm (scalar chain, one row at a time)
#pragma unroll
  for (int rt = 0; rt < 2; ++rt)
#pragma unroll
    for (int j = 0; j < 4; ++j) {
      float mx = acc[rt][0][j];
#pragma unroll
      for (int ct = 1; ct < 8; ++ct) mx = fmaxf(mx, acc[rt][ct][j]);
#pragma unroll
      for (int msk = 1; msk < 16; msk <<= 1) mx = fmaxf(mx, __shfl_xor(mx, msk, 64));
      if (cl == 0) redm[wv * 32 + rt * 16 + g * 4 + j] = mx;
    }
  __syncthreads();

  // global row max (threads 0..31)
  if (tid < 32) {
    float mx = redm[tid];
#pragma unroll
    for (int w = 1; w < 8; ++w) mx = fmaxf(mx, redm[w * 32 + tid]);
    gmbuf[tid] = mx;
  }
  __syncthreads();

  // per-wave per-row partial sumexp vs global max -> reds
#pragma unroll
  for (int rt = 0; rt < 2; ++rt)
#pragma unroll
    for (int j = 0; j < 4; ++j) {
      int row = rt * 16 + g * 4 + j;
      float gm = gmbuf[row];
      float ps = 0.f;
#pragma unroll
      for (int ct = 0; ct < 8; ++ct) ps += __expf(acc[rt][ct][j] - gm);
#pragma unroll
      for (int msk = 1; msk < 16; msk <<= 1) ps += __shfl_xor(ps, msk, 64);
      if (cl == 0) reds[wv * 32 + row] = ps;
    }
  __syncthreads();

  // finalize lse per row (threads 0..31)
  if (tid < 32) {
    float s = reds[tid];
#pragma unroll
    for (int w = 1; w < 8; ++w) s += reds[w * 32 + tid];
    lsebuf[tid] = gmbuf[tid] + __logf(s);
  }
  __syncthreads();

  // store
#pragma unroll
  for (int rt = 0; rt < 2; ++rt)
#pragma unroll
    for (int j = 0; j < 4; ++j) {
      int row = rt * 16 + g * 4 + j;
      float lse = lsebuf[row];
      int n = (b * T_ + t0 + (row >> 3)) * S_ + s0 + (row & 7);
      float* op = out + (size_t)n * V_ + wv * 128 + cl;
#pragma unroll
      for (int ct = 0; ct < 8; ++ct) op[ct * 16] = acc[rt][ct][j] - lse;
    }
}

// ---------------------------------------------------------------------------
extern "C" void kernel_launch(void* const* d_in, const int* in_sizes, int n_in,
                              void* d_out, int out_size, void* d_ws, size_t ws_size,
                              hipStream_t stream) {
  const float* src = (const float*)d_in[0];  // [4,160,640]
  const float* tgt = (const float*)d_in[1];  // [4,80,640]
  const float* W1  = (const float*)d_in[2];  // [640,1024]
  const float* b1  = (const float*)d_in[3];  // [1024]
  const float* W2  = (const float*)d_in[4];  // [1024,1024]
  const float* b2  = (const float*)d_in[5];  // [1024]
  float* out = (float*)d_out;

  char* ws = (char*)d_ws;
  s16x8* W1p = (s16x8*)(ws);             // 1,310,720 B
  s16x8* W2p = (s16x8*)(ws + 1310720);   // 2,097,152 B
  float* P   = (float*)(ws + 3407872);   // 2,621,440 B  (src@W1 + b1)
  float* Q   = (float*)(ws + 6029312);   // 1,310,720 B  (tgt@W1)
  // total ws use: 7,340,032 B

  prep_weights<<<832, 256, 0, stream>>>(W1, W2, W1p, W2p);
  pq_gemm<<<120, 512, 0, stream>>>(src, tgt, W1p, b1, P, Q);
  joint_main<<<1600, 512, 0, stream>>>(P, Q, W2p, b2, out);
}